// Round 2
// baseline (242.868 us; speedup 1.0000x reference)
//
#include <hip/hip_runtime.h>

// Linear attention (ELU+1 feature map), N=8, L=S=8192, H=8, D=32, fp32.
// out[n,l,h,v] = (q . KV[n,h,:,v]) / (q . Ksum[n,h,:] + eps),  q = elu(Q)+1
// KV = sum_s elu1(K_s) outer V_s ; Ksum = sum_s elu1(K_s)
// (the /S and *S of the reference cancel exactly: /8192 is a lossless exponent shift)

#define NN 8
#define LL 8192
#define SS 8192
#define HH 8
#define DD 32
#define HD 256
#define EPSF 1e-6f

#define KV_FLOATS (NN*HH*DD*DD)              // 65536
#define FINAL_FLOATS (KV_FLOATS + NN*HH*DD)  // 67584

// ---- phase 1: 512 blocks x 256 thr, tile 8d x 4v per thread ----
#define P1_CHUNKS 64
#define P1_BLOCKS (NN*P1_CHUNKS)   // 512
#define P1_CS (SS/P1_CHUNKS)       // 128 s per block
#define P1_TS 16                   // s staged per iteration (32 KB LDS)
#define PBLK 8448                  // floats per partial block (8192 KV + 256 ksum)

// ---- phase 2: 2048 blocks x 256 thr, h-pair per block, tile 4l x 8v ----
#define P2_I 128                   // l per block
#define P2_BLOCKS (NN*4*(LL/P2_I)) // 8n * 4 hpair * 64 = 2048

__device__ __forceinline__ float elu1(float x) {
    return x > 0.f ? x + 1.f : __expf(x);
}
#define ELU4(v) { v.x = elu1(v.x); v.y = elu1(v.y); v.z = elu1(v.z); v.w = elu1(v.w); }

// ============================ phase 1 =====================================
// thread t: h = t>>5, dO = (t>>3)&3, vO = t&7.
// acc[8][4] covers d = dO*8..+7, v = vO*4..+3 for head h.
// LDS reads/s: 2 b128 K (2-way alias) + 1 b128 V (2-way) for 32 FMA.
template<bool ATOMIC>
__global__ __launch_bounds__(256)
void la_phase1(const float* __restrict__ keys, const float* __restrict__ values,
               float* __restrict__ outbuf) {
    __shared__ float4 lK4[P1_TS*64];   // [s][64 float4] 16 KB
    __shared__ float4 lV4[P1_TS*64];   // 16 KB
    const int t = threadIdx.x;
    const int b = blockIdx.x;
    const int n = b / P1_CHUNKS;
    const int s0 = (b % P1_CHUNKS) * P1_CS;
    const int h  = t >> 5;
    const int dO = (t >> 3) & 3;
    const int vO = t & 7;

    const float4* Kg = (const float4*)(keys   + ((size_t)n*SS + s0)*HD);
    const float4* Vg = (const float4*)(values + ((size_t)n*SS + s0)*HD);

    float4 acc[8];
#pragma unroll
    for (int i = 0; i < 8; ++i) acc[i] = make_float4(0.f,0.f,0.f,0.f);
    float4 ksa = make_float4(0.f,0.f,0.f,0.f), ksb = make_float4(0.f,0.f,0.f,0.f);

    // prefetch first 16-s chunk: 1024 float4/tensor, 4 per thread
    float4 kp[4], vp[4];
#pragma unroll
    for (int r = 0; r < 4; ++r) { kp[r] = Kg[t + 256*r]; vp[r] = Vg[t + 256*r]; }

    const int kbase = h*8 + dO*2;   // float4 col of K oct
    const int vbase = h*8 + vO;     // float4 col of V quad

    for (int si = 0; si < P1_CS; si += P1_TS) {
#pragma unroll
        for (int r = 0; r < 4; ++r) ELU4(kp[r]);
        __syncthreads();            // previous compute finished reading LDS
#pragma unroll
        for (int r = 0; r < 4; ++r) { lK4[t + 256*r] = kp[r]; lV4[t + 256*r] = vp[r]; }
        __syncthreads();
        if (si + P1_TS < P1_CS) {   // prefetch next chunk; overlaps compute below
            const int nb = (si + P1_TS) * 64;
#pragma unroll
            for (int r = 0; r < 4; ++r) { kp[r] = Kg[nb + t + 256*r]; vp[r] = Vg[nb + t + 256*r]; }
        }
#pragma unroll
        for (int i = 0; i < P1_TS; ++i) {
            const float4 k0 = lK4[i*64 + kbase];
            const float4 k1 = lK4[i*64 + kbase + 1];
            const float4 vv = lV4[i*64 + vbase];
            ksa.x += k0.x; ksa.y += k0.y; ksa.z += k0.z; ksa.w += k0.w;
            ksb.x += k1.x; ksb.y += k1.y; ksb.z += k1.z; ksb.w += k1.w;
#define P1F(A,S) A.x=fmaf(S,vv.x,A.x); A.y=fmaf(S,vv.y,A.y); A.z=fmaf(S,vv.z,A.z); A.w=fmaf(S,vv.w,A.w);
            P1F(acc[0],k0.x) P1F(acc[1],k0.y) P1F(acc[2],k0.z) P1F(acc[3],k0.w)
            P1F(acc[4],k1.x) P1F(acc[5],k1.y) P1F(acc[6],k1.z) P1F(acc[7],k1.w)
#undef P1F
        }
    }

    if (ATOMIC) {
        float* kvb = outbuf + (size_t)n*(HH*DD*DD) + h*(DD*DD) + (dO*8)*DD + vO*4;
#pragma unroll
        for (int dd = 0; dd < 8; ++dd) {
            atomicAdd(kvb + dd*DD + 0, acc[dd].x);
            atomicAdd(kvb + dd*DD + 1, acc[dd].y);
            atomicAdd(kvb + dd*DD + 2, acc[dd].z);
            atomicAdd(kvb + dd*DD + 3, acc[dd].w);
        }
        if (vO == 0) {
            float* kb = outbuf + KV_FLOATS + n*HD + h*DD + dO*8;
            atomicAdd(kb+0, ksa.x); atomicAdd(kb+1, ksa.y); atomicAdd(kb+2, ksa.z); atomicAdd(kb+3, ksa.w);
            atomicAdd(kb+4, ksb.x); atomicAdd(kb+5, ksb.y); atomicAdd(kb+6, ksb.z); atomicAdd(kb+7, ksb.w);
        }
    } else {
        float4* pb4 = (float4*)(outbuf + (size_t)b * PBLK);
#pragma unroll
        for (int dd = 0; dd < 8; ++dd) pb4[h*256 + (dO*8+dd)*8 + vO] = acc[dd];
        if (vO == 0) { pb4[2048 + h*8 + dO*2] = ksa; pb4[2048 + h*8 + dO*2 + 1] = ksb; }
    }
}

// ============================ reduce ======================================
// Sums P1_CHUNKS partials per n. 264 blocks x 256 = 67584 output floats.
__global__ __launch_bounds__(256)
void la_reduce(const float* __restrict__ part, float* __restrict__ finalbuf) {
    const int o = blockIdx.x * 256 + threadIdx.x;   // 0 .. FINAL_FLOATS-1
    const int n = o / PBLK;
    const int e = o - n * PBLK;
    const float* p = part + (size_t)(n * P1_CHUNKS) * PBLK + e;
    float s = 0.f;
#pragma unroll 8
    for (int c = 0; c < P1_CHUNKS; ++c) s += p[(size_t)c * PBLK];
    if (e < HH*DD*DD) finalbuf[(size_t)n*(HH*DD*DD) + e] = s;
    else              finalbuf[KV_FLOATS + n*HD + (e - HH*DD*DD)] = s;
}

// ============================ phase 2 =====================================
// block = (n, h-pair, 128-l chunk). Q staged TRANSPOSED: lqt[hh][d][i'] with
// i' = i ^ ((d>>2)<<2)  (XOR swizzle: write side spreads all 32 banks, read
// side stays a contiguous quad at position lq^dq -> data of quad lq).
// compute thread: voct = t&3, hh = (t>>2)&1, lq = t>>3; tile 4l x 8v.
// Per d: 1 b128 q + 2 b128 KV for 32 FMA (+Z FMAs; Ksum quad amortized /4).
__global__ __launch_bounds__(256)
void la_phase2(const float* __restrict__ queries, const float* __restrict__ finalbuf,
               float* __restrict__ out) {
    __shared__ float4 lqt4s[2*DD*P2_I/4];  // 2048 f4 = 32 KB  [hh][d][i']
    __shared__ float4 lkv4[2*DD*DD/4];     // 512 f4 = 8 KB    [hh][d][v]
    __shared__ float4 lks4[16];            // [hh][d]
    float* lqt = (float*)lqt4s;

    const int t = threadIdx.x;
    const int b = blockIdx.x;
    const int n  = b >> 8;
    const int hp = (b >> 6) & 3;
    const int l0 = (b & 63) * P2_I;

    // stage KV (2 heads, 2048 floats) + Ksum (64 floats)
    const float4* fin4 = (const float4*)finalbuf;
    lkv4[t]       = fin4[(size_t)n*2048 + hp*512 + t];
    lkv4[t + 256] = fin4[(size_t)n*2048 + hp*512 + t + 256];
    if (t < 16) lks4[t] = fin4[KV_FLOATS/4 + n*64 + hp*16 + t];

    // stage Q transposed + swizzled (elu applied in regs)
    const int irow = t >> 4;        // 0..15
    const int shh  = (t >> 3) & 1;
    const int d4   = t & 7;
    const float4* Qg4 = (const float4*)queries;
    const size_t qb = ((size_t)n*LL + l0)*64 + (size_t)(hp*16 + shh*8 + d4);
    float* dst0 = lqt + shh*4096 + (d4*4)*P2_I;
#pragma unroll
    for (int k = 0; k < 8; ++k) {
        const int i = irow + k*16;
        float4 qv = Qg4[qb + (size_t)i*64];
        ELU4(qv);
        const int ip = i ^ (d4 << 2);
        dst0[ip] = qv.x; dst0[P2_I + ip] = qv.y; dst0[2*P2_I + ip] = qv.z; dst0[3*P2_I + ip] = qv.w;
    }
    __syncthreads();

    const int voct = t & 3;
    const int hh   = (t >> 2) & 1;
    const int lq   = t >> 3;        // 0..31

    float4 a0[4], a1[4];
#pragma unroll
    for (int i = 0; i < 4; ++i) { a0[i] = make_float4(0.f,0.f,0.f,0.f); a1[i] = make_float4(0.f,0.f,0.f,0.f); }
    float z0 = 0.f, z1 = 0.f, z2 = 0.f, z3 = 0.f;

    const float4* lqt4 = (const float4*)lqt;
    const int qbase  = hh*1024;            // float4 base of lqt[hh]
    const int kvbase = hh*256 + voct*2;    // (hh*32+d)*8 + voct*2, d-part added below

#define FMA8(L, QS) \
    a0[L].x = fmaf(QS, kA.x, a0[L].x); a0[L].y = fmaf(QS, kA.y, a0[L].y); \
    a0[L].z = fmaf(QS, kA.z, a0[L].z); a0[L].w = fmaf(QS, kA.w, a0[L].w); \
    a1[L].x = fmaf(QS, kB.x, a1[L].x); a1[L].y = fmaf(QS, kB.y, a1[L].y); \
    a1[L].z = fmaf(QS, kB.z, a1[L].z); a1[L].w = fmaf(QS, kB.w, a1[L].w);

#define P2S(J, KSD) { \
    const int d = dq*4 + (J); \
    const float4 qv = lqt4[qbase + d*32 + (lq ^ dq)]; \
    const float4 kA = lkv4[kvbase + d*8]; \
    const float4 kB = lkv4[kvbase + d*8 + 1]; \
    z0 = fmaf(qv.x, KSD, z0); z1 = fmaf(qv.y, KSD, z1); \
    z2 = fmaf(qv.z, KSD, z2); z3 = fmaf(qv.w, KSD, z3); \
    FMA8(0, qv.x) FMA8(1, qv.y) FMA8(2, qv.z) FMA8(3, qv.w) }

#pragma unroll
    for (int dq = 0; dq < 8; ++dq) {
        const float4 ks = lks4[hh*8 + dq];
        P2S(0, ks.x) P2S(1, ks.y) P2S(2, ks.z) P2S(3, ks.w)
    }
#undef P2S
#undef FMA8

    float4* out4 = (float4*)out;
    const size_t ob = ((size_t)n*LL + l0 + lq*4)*64 + (size_t)(hp*16 + hh*8 + voct*2);
#define P2OUT(L, ZV) { \
    const float zi = 1.0f/((ZV) + EPSF); \
    float4 r0 = a0[L], r1 = a1[L]; \
    r0.x*=zi; r0.y*=zi; r0.z*=zi; r0.w*=zi; r1.x*=zi; r1.y*=zi; r1.z*=zi; r1.w*=zi; \
    out4[ob + (size_t)(L)*64] = r0; out4[ob + (size_t)(L)*64 + 1] = r1; }
    P2OUT(0, z0) P2OUT(1, z1) P2OUT(2, z2) P2OUT(3, z3)
#undef P2OUT
}

// ============================ launch ======================================
extern "C" void kernel_launch(void* const* d_in, const int* in_sizes, int n_in,
                              void* d_out, int out_size, void* d_ws, size_t ws_size,
                              hipStream_t stream) {
    const float* q = (const float*)d_in[0];
    const float* k = (const float*)d_in[1];
    const float* v = (const float*)d_in[2];
    float* out = (float*)d_out;

    const size_t partial_floats = (size_t)P1_BLOCKS * PBLK;
    const size_t need = (partial_floats + FINAL_FLOATS) * sizeof(float);

    if (ws_size >= need) {
        float* part = (float*)d_ws;
        float* fin  = part + partial_floats;
        la_phase1<false><<<dim3(P1_BLOCKS), dim3(256), 0, stream>>>(k, v, part);
        la_reduce<<<dim3(FINAL_FLOATS/256), dim3(256), 0, stream>>>(part, fin);
        la_phase2<<<dim3(P2_BLOCKS), dim3(256), 0, stream>>>(q, fin, out);
    } else {
        // fallback: tiny ws -> atomic accumulation into final buffer
        float* fin = (float*)d_ws;
        hipMemsetAsync(fin, 0, FINAL_FLOATS*sizeof(float), stream);
        la_phase1<true><<<dim3(P1_BLOCKS), dim3(256), 0, stream>>>(k, v, fin);
        la_phase2<<<dim3(P2_BLOCKS), dim3(256), 0, stream>>>(q, fin, out);
    }
}